// Round 2
// baseline (76130.469 us; speedup 1.0000x reference)
//
#include <hip/hip_runtime.h>
#include <hip/hip_bf16.h>
#include <math.h>

using bf16 = __hip_bfloat16;

// ---------------- problem dims ----------------
static constexpr int  BB  = 2048;
static constexpr int  IH  = 23, IW = 31;   // stage 1 spatial
static constexpr int  PH  = 11, PW = 15;   // after pool1
static constexpr int  QH  = 5,  QW = 7;    // after pool2
static constexpr long NSITE1 = (long)BB * IH * IW;   // 1,460,224
static constexpr long NSITE2 = (long)BB * PH * PW;   //   337,920
static constexpr long NSITE3 = (long)BB * QH * QW;   //    71,680

// ---------------- workspace layout ----------------
// float region:
//   [0,642)   BN sum/sumsq accumulators + 2 counts  (zeroed via memset 4096B)
//   [704,1344) scale/shift (written before read)
//   [2048, +NSITE1+NSITE2+NSITE3) masks m0,m1,m2
// bf16 region (starts at float offset 1,871,872 = byte 7,487,488):
//   region A: 43,253,760 elems   region B: 46,727,168 elems
// total = 7,487,488 + 2*(43,253,760+46,727,168) = 187,449,344 B ~ 179 MB
static constexpr long OFF_S1 = 0,   OFF_Q1 = 64;
static constexpr long OFF_S2 = 128, OFF_Q2 = 192;
static constexpr long OFF_S3 = 256, OFF_Q3 = 320;
static constexpr long OFF_S4 = 384, OFF_Q4 = 512;
static constexpr long OFF_N1 = 640, OFF_N2 = 641;
static constexpr long OFF_SC1 = 704,  OFF_SH1 = 768;
static constexpr long OFF_SC2 = 832,  OFF_SH2 = 896;
static constexpr long OFF_SC3 = 960,  OFF_SH3 = 1024;
static constexpr long OFF_SC4 = 1088, OFF_SH4 = 1216;
static constexpr long OFF_M0 = 2048;
static constexpr long OFF_M1 = OFF_M0 + NSITE1;
static constexpr long OFF_M2 = OFF_M1 + NSITE2;
static constexpr long OFF_BF = 1871872;             // float offset where bf16 area starts
static constexpr long SZ_A   = 43253760L;           // bf16 elems

__device__ __forceinline__ float sigmoidf_(float x) { return 1.f / (1.f + __expf(-x)); }
__device__ __forceinline__ float b2f(bf16 v) { return __bfloat162float(v); }
__device__ __forceinline__ bf16  f2b(float v) { return __float2bfloat16(v); }

// load 8 consecutive bf16 (16B aligned) -> 8 floats
__device__ __forceinline__ void ld8(const bf16* p, float* f) {
    union { uint4 u; unsigned short s[8]; } cv;
    cv.u = *(const uint4*)p;
#pragma unroll
    for (int i = 0; i < 8; i++) f[i] = __uint_as_float(((unsigned int)cv.s[i]) << 16);
}

// ---------------- prep: int mask -> float, xm = bf16(x*m) ----------------
__global__ void prep_k(const float* __restrict__ x, const int* __restrict__ mask,
                       float* __restrict__ m0, bf16* __restrict__ xm) {
    long idx = (long)blockIdx.x * 256 + threadIdx.x;
    if (idx >= NSITE1) return;
    float m = (mask[idx] != 0) ? 1.f : 0.f;
    m0[idx] = m;
    xm[idx * 2 + 0] = f2b(x[idx * 2 + 0] * m);
    xm[idx * 2 + 1] = f2b(x[idx * 2 + 1] * m);
}

// ---------------- conv1: 2->16, naive (tiny) ----------------
__global__ void conv1_k(const bf16* __restrict__ xm, const float* __restrict__ Wt,
                        const float* __restrict__ m0, bf16* __restrict__ out) {
    const int CIN = 2, COUT = 16, H = IH, W = IW;
    long idx = (long)blockIdx.x * 256 + threadIdx.x;
    long total = NSITE1 * COUT;
    if (idx >= total) return;
    int co = idx % COUT; long site = idx / COUT;
    if (m0[site] == 0.f) { out[idx] = f2b(0.f); return; }
    int w = (int)(site % W); long t2 = site / W; int h = (int)(t2 % H);
    float acc = 0.f;
    for (int kh = 0; kh < 3; kh++) {
        int hh = h + kh - 1; if (hh < 0 || hh >= H) continue;
        for (int kw = 0; kw < 3; kw++) {
            int ww = w + kw - 1; if (ww < 0 || ww >= W) continue;
            long ns = site + (long)(kh - 1) * W + (kw - 1);
            const bf16* ip = xm + ns * CIN;
            const float* wp = Wt + ((kh * 3 + kw) * CIN) * COUT + co;
            acc += b2f(ip[0]) * wp[0] + b2f(ip[1]) * wp[COUT];
        }
    }
    out[idx] = f2b(acc);
}

// ---------------- generic tiled conv 3x3 SAME, masked output ----------------
// block = 256 threads: c = tid % COUT, site-subgroup sg = tid / COUT
template<int CIN, int COUT, int S>
__global__ void conv3x3_tile(const bf16* __restrict__ in, const float* __restrict__ Wt,
                             const float* __restrict__ mask, bf16* __restrict__ out,
                             int B, int H, int W) {
    constexpr int NS  = 256 / COUT;
    constexpr int SPT = S / NS;
    __shared__ float act[S][CIN];
    const int tid = threadIdx.x;
    const int c  = tid % COUT;
    const int sg = tid / COUT;
    const long nsites = (long)B * H * W;
    const long base = (long)blockIdx.x * S;

    float acc[SPT];
#pragma unroll
    for (int i = 0; i < SPT; i++) acc[i] = 0.f;

    for (int kh = 0; kh < 3; kh++)
    for (int kw = 0; kw < 3; kw++) {
        __syncthreads();
        for (int idx = tid * 8; idx < S * CIN; idx += 256 * 8) {
            int s = idx / CIN, ci = idx % CIN;
            long site = base + s;
            float f[8];
#pragma unroll
            for (int i = 0; i < 8; i++) f[i] = 0.f;
            if (site < nsites) {
                int w = (int)(site % W); long t2 = site / W; int h = (int)(t2 % H);
                int hh = h + kh - 1, ww = w + kw - 1;
                if (hh >= 0 && hh < H && ww >= 0 && ww < W) {
                    long nsi = site + (long)(kh - 1) * W + (kw - 1);
                    ld8(in + nsi * CIN + ci, f);
                }
            }
#pragma unroll
            for (int i = 0; i < 8; i++) act[s][ci + i] = f[i];
        }
        __syncthreads();
        const float* wp = Wt + ((kh * 3 + kw) * CIN) * COUT + c;
        for (int ci = 0; ci < CIN; ci += 4) {
            float w0 = wp[(ci + 0) * COUT], w1 = wp[(ci + 1) * COUT];
            float w2 = wp[(ci + 2) * COUT], w3 = wp[(ci + 3) * COUT];
#pragma unroll
            for (int t = 0; t < SPT; t++) {
                int s = sg * SPT + t;
                float4 a = *(const float4*)&act[s][ci];
                acc[t] += a.x * w0 + a.y * w1 + a.z * w2 + a.w * w3;
            }
        }
    }
#pragma unroll
    for (int t = 0; t < SPT; t++) {
        long site = base + sg * SPT + t;
        if (site < nsites) out[site * COUT + c] = f2b((mask[site] > 0.f) ? acc[t] : 0.f);
    }
}

// ---------------- BN stats: per-channel sum/sumsq (+ optional site count) ----------------
template<int C>
__global__ void bn_stats(const bf16* __restrict__ v, const float* __restrict__ mask,
                         float* __restrict__ sum, float* __restrict__ sumsq,
                         float* __restrict__ count, long nsites) {
    __shared__ float s_sum[C], s_ss[C];
    __shared__ float s_cnt;
    int tid = threadIdx.x;
    if (tid < C) { s_sum[tid] = 0.f; s_ss[tid] = 0.f; }
    if (tid == 0) s_cnt = 0.f;
    __syncthreads();
    const int c = tid % C;
    long total = nsites * C;
    long stride = (long)gridDim.x * blockDim.x;
    float ls = 0.f, lss = 0.f, lc = 0.f;
    for (long e = (long)blockIdx.x * blockDim.x + tid; e < total; e += stride) {
        float x = b2f(v[e]);
        ls += x; lss += x * x;
        if (count != nullptr && c == 0) lc += (mask[e / C] > 0.f) ? 1.f : 0.f;
    }
    atomicAdd(&s_sum[c], ls);
    atomicAdd(&s_ss[c], lss);
    if (count != nullptr && c == 0) atomicAdd(&s_cnt, lc);
    __syncthreads();
    if (tid < C) { atomicAdd(&sum[tid], s_sum[tid]); atomicAdd(&sumsq[tid], s_ss[tid]); }
    if (count != nullptr && tid == 0) atomicAdd(count, s_cnt);
}

// ---------------- BN param: scale/shift from stats ----------------
template<int C>
__global__ void bn_param(const float* __restrict__ sum, const float* __restrict__ ss,
                         const float* __restrict__ count,
                         const float* __restrict__ g, const float* __restrict__ b,
                         float* __restrict__ scale, float* __restrict__ shift) {
    int c = threadIdx.x;
    if (c >= C) return;
    float n = fmaxf(count[0], 1.f);
    float mean = sum[c] / n;
    float var  = ss[c] / n - mean * mean;
    float sc = (1.f / sqrtf(var + 1e-4f)) * g[c];
    scale[c] = sc;
    shift[c] = b[c] - mean * sc;
}

// ---------------- BN apply (+ReLU, masked), in-place ----------------
template<int C>
__global__ void bn_apply(bf16* __restrict__ v, const float* __restrict__ mask,
                         const float* __restrict__ scale, const float* __restrict__ shift,
                         long nsites) {
    long idx = (long)blockIdx.x * 256 + threadIdx.x;
    if (idx >= nsites * C) return;
    int c = idx % C; long site = idx / C;
    float val = 0.f;
    if (mask[site] > 0.f) val = fmaxf(b2f(v[idx]) * scale[c] + shift[c], 0.f);
    v[idx] = f2b(val);
}

// ---------------- maxpool 3x3 stride 2 VALID + mask pool ----------------
template<int C>
__global__ void maxpool_k(const bf16* __restrict__ in, const float* __restrict__ min_,
                          bf16* __restrict__ out, float* __restrict__ mout,
                          int B, int H, int W, int OH, int OW) {
    long idx = (long)blockIdx.x * 256 + threadIdx.x;
    long total = (long)B * OH * OW * C;
    if (idx >= total) return;
    int c = idx % C; long osite = idx / C;
    int ow = (int)(osite % OW); long t2 = osite / OW; int oh = (int)(t2 % OH); long b = t2 / OH;
    float mm = 0.f, p = -1e30f;
    for (int kh = 0; kh < 3; kh++)
    for (int kw = 0; kw < 3; kw++) {
        int h = oh * 2 + kh, w = ow * 2 + kw;
        long is = ((long)b * H + h) * W + w;
        float mv = min_[is];
        if (mv > 0.f) { mm = 1.f; p = fmaxf(p, b2f(in[is * C + c])); }
    }
    out[idx] = f2b((mm > 0.f) ? p : 0.f);
    if (c == 0) mout[osite] = mm;
}

// ---------------- ConvLSTM gates (i,o,g; f dead since c0=0) + LSTM ----------------
// block = 256 threads (c = tid), S=16 sites per block; output gout[site*256+c]
__global__ void gates_lstm(const bf16* __restrict__ p2, const float* __restrict__ Wl,
                           const float* __restrict__ bl, const float* __restrict__ m2,
                           bf16* __restrict__ gout) {
    constexpr int CIN = 128, S = 16;
    __shared__ float act[S][CIN];
    const int tid = threadIdx.x;
    const long base = (long)blockIdx.x * S;
    float ai[S], ao[S], ag[S];
#pragma unroll
    for (int s = 0; s < S; s++) { ai[s] = 0.f; ao[s] = 0.f; ag[s] = 0.f; }

    for (int kh = 0; kh < 3; kh++)
    for (int kw = 0; kw < 3; kw++) {
        __syncthreads();
        {   // stage S*CIN = 2048 bf16: each thread one 8-elem chunk
            int idx = tid * 8;
            int s = idx / CIN, ci = idx % CIN;
            long site = base + s;
            float f[8];
#pragma unroll
            for (int i = 0; i < 8; i++) f[i] = 0.f;
            if (site < NSITE3) {
                int w = (int)(site % QW); long t2 = site / QW; int h = (int)(t2 % QH);
                int hh = h + kh - 1, ww = w + kw - 1;
                if (hh >= 0 && hh < QH && ww >= 0 && ww < QW) {
                    long nsi = site + (long)(kh - 1) * QW + (kw - 1);
                    ld8(p2 + nsi * CIN + ci, f);
                }
            }
#pragma unroll
            for (int i = 0; i < 8; i++) act[s][ci + i] = f[i];
        }
        __syncthreads();
        const float* wp = Wl + ((kh * 3 + kw) * CIN) * 1024 + tid;  // i +0, o +512, g +768
        for (int ci = 0; ci < CIN; ci += 4) {
            float wi0 = wp[(ci + 0) * 1024 +   0], wi1 = wp[(ci + 1) * 1024 +   0];
            float wi2 = wp[(ci + 2) * 1024 +   0], wi3 = wp[(ci + 3) * 1024 +   0];
            float wo0 = wp[(ci + 0) * 1024 + 512], wo1 = wp[(ci + 1) * 1024 + 512];
            float wo2 = wp[(ci + 2) * 1024 + 512], wo3 = wp[(ci + 3) * 1024 + 512];
            float wg0 = wp[(ci + 0) * 1024 + 768], wg1 = wp[(ci + 1) * 1024 + 768];
            float wg2 = wp[(ci + 2) * 1024 + 768], wg3 = wp[(ci + 3) * 1024 + 768];
#pragma unroll
            for (int s = 0; s < S; s++) {
                float4 a = *(const float4*)&act[s][ci];
                ai[s] += a.x * wi0 + a.y * wi1 + a.z * wi2 + a.w * wi3;
                ao[s] += a.x * wo0 + a.y * wo1 + a.z * wo2 + a.w * wo3;
                ag[s] += a.x * wg0 + a.y * wg1 + a.z * wg2 + a.w * wg3;
            }
        }
    }
#pragma unroll
    for (int s = 0; s < S; s++) {
        long site = base + s;
        if (site >= NSITE3) continue;
        float m = m2[site];
        float val = 0.f;
        if (m > 0.f) {
            float i_ = ai[s] + bl[tid];
            float o_ = ao[s] + bl[512 + tid];
            float g_ = ag[s] + bl[768 + tid];
            float ct = sigmoidf_(i_) * tanhf(g_);
            val = sigmoidf_(o_) * tanhf(ct);
        }
        gout[site * 256 + tid] = f2b(val);   // [site, c] layout, coalesced
    }
}

// ---------------- FC1: y1[b,j] = relu(sum_k flat[b,k]*lw1[k,j] + lb1[j]) ----------------
// flat[b, k=c*35+hw] lives at gout[(b*35+hw)*256 + c]. 32 batch rows per thread.
__global__ void fc1_k(const bf16* __restrict__ gout, const float* __restrict__ lw1,
                      const float* __restrict__ lb1, bf16* __restrict__ y1) {
    int j  = (blockIdx.x % 4) * 256 + threadIdx.x;
    int b0 = (blockIdx.x / 4) * 32;
    float acc[32];
#pragma unroll
    for (int t = 0; t < 32; t++) acc[t] = 0.f;
    for (int hw = 0; hw < 35; hw++) {
        for (int c8 = 0; c8 < 256; c8 += 8) {
            float w[8];
#pragma unroll
            for (int i = 0; i < 8; i++)
                w[i] = lw1[(long)((c8 + i) * 35 + hw) * 1024 + j];
#pragma unroll
            for (int t = 0; t < 32; t++) {
                float f[8];
                ld8(&gout[((long)(b0 + t) * 35 + hw) * 256 + c8], f);
#pragma unroll
                for (int i = 0; i < 8; i++) acc[t] += f[i] * w[i];
            }
        }
    }
    float bias = lb1[j];
#pragma unroll
    for (int t = 0; t < 32; t++)
        y1[(long)(b0 + t) * 1024 + j] = f2b(fmaxf(acc[t] + bias, 0.f));
}

// ---------------- FC2: [2048,1024] @ [1024,420] + bias ----------------
__global__ void fc2_k(const bf16* __restrict__ y1, const float* __restrict__ lw2,
                      const float* __restrict__ lb2, float* __restrict__ out) {
    long idx = (long)blockIdx.x * 256 + threadIdx.x;
    long total = (long)BB * 420;
    if (idx >= total) return;
    int j = (int)(idx % 420); long b = idx / 420;
    float acc = lb2[j];
    const bf16* yr = y1 + b * 1024;
    for (int k8 = 0; k8 < 1024; k8 += 8) {
        float f[8];
        ld8(yr + k8, f);
#pragma unroll
        for (int i = 0; i < 8; i++) acc += f[i] * lw2[(long)(k8 + i) * 420 + j];
    }
    out[idx] = acc;
}

// ---------------- launch ----------------
extern "C" void kernel_launch(void* const* d_in, const int* in_sizes, int n_in,
                              void* d_out, int out_size, void* d_ws, size_t ws_size,
                              hipStream_t stream) {
    const float* x    = (const float*)d_in[0];
    const int*   mask = (const int*)d_in[1];
    const float* W1 = (const float*)d_in[2];
    const float* g1 = (const float*)d_in[3];
    const float* b1 = (const float*)d_in[4];
    const float* W2 = (const float*)d_in[5];
    const float* g2 = (const float*)d_in[6];
    const float* b2 = (const float*)d_in[7];
    const float* W3 = (const float*)d_in[8];
    const float* g3 = (const float*)d_in[9];
    const float* b3 = (const float*)d_in[10];
    const float* W4 = (const float*)d_in[11];
    const float* g4 = (const float*)d_in[12];
    const float* b4 = (const float*)d_in[13];
    const float* Wl = (const float*)d_in[14];
    const float* bl = (const float*)d_in[15];
    const float* lw1 = (const float*)d_in[16];
    const float* lb1 = (const float*)d_in[17];
    const float* lw2 = (const float*)d_in[18];
    const float* lb2 = (const float*)d_in[19];
    float* out = (float*)d_out;

    float* ws = (float*)d_ws;
    float* m0 = ws + OFF_M0;
    float* m1 = ws + OFF_M1;
    float* m2 = ws + OFF_M2;
    bf16* bufA = (bf16*)(ws + OFF_BF);
    bf16* bufB = bufA + SZ_A;

    bf16* c1   = bufA;            // [NSITE1,16]
    bf16* xm   = bufB;            // [NSITE1,2]  (dead after conv1)
    bf16* c2   = bufB;            // [NSITE1,32]
    bf16* p1   = bufA;            // [NSITE2,32]
    bf16* c3   = bufB;            // [NSITE2,64]
    bf16* c4   = bufA;            // [NSITE2,128]
    bf16* p2   = bufB;            // [NSITE3,128]
    bf16* gout = bufA;            // [NSITE3,256]
    bf16* y1   = bufB;            // [2048,1024]

    // zero BN stat accumulators (sums/sumsq/counts)
    hipMemsetAsync(ws, 0, 4096, stream);

    prep_k<<<(int)((NSITE1 + 255) / 256), 256, 0, stream>>>(x, mask, m0, xm);

    conv1_k<<<(int)(NSITE1 * 16 / 256), 256, 0, stream>>>(xm, W1, m0, c1);
    bn_stats<16><<<1280, 256, 0, stream>>>(c1, m0, ws + OFF_S1, ws + OFF_Q1, ws + OFF_N1, NSITE1);
    bn_param<16><<<1, 16, 0, stream>>>(ws + OFF_S1, ws + OFF_Q1, ws + OFF_N1, g1, b1, ws + OFF_SC1, ws + OFF_SH1);
    bn_apply<16><<<(int)(NSITE1 * 16 / 256), 256, 0, stream>>>(c1, m0, ws + OFF_SC1, ws + OFF_SH1, NSITE1);

    conv3x3_tile<16, 32, 16><<<(int)(NSITE1 / 16), 256, 0, stream>>>(c1, W2, m0, c2, BB, IH, IW);
    bn_stats<32><<<1280, 256, 0, stream>>>(c2, m0, ws + OFF_S2, ws + OFF_Q2, nullptr, NSITE1);
    bn_param<32><<<1, 32, 0, stream>>>(ws + OFF_S2, ws + OFF_Q2, ws + OFF_N1, g2, b2, ws + OFF_SC2, ws + OFF_SH2);
    bn_apply<32><<<(int)(NSITE1 * 32 / 256), 256, 0, stream>>>(c2, m0, ws + OFF_SC2, ws + OFF_SH2, NSITE1);

    maxpool_k<32><<<(int)(NSITE2 * 32 / 256), 256, 0, stream>>>(c2, m0, p1, m1, BB, IH, IW, PH, PW);

    conv3x3_tile<32, 64, 16><<<(int)(NSITE2 / 16), 256, 0, stream>>>(p1, W3, m1, c3, BB, PH, PW);
    bn_stats<64><<<1280, 256, 0, stream>>>(c3, m1, ws + OFF_S3, ws + OFF_Q3, ws + OFF_N2, NSITE2);
    bn_param<64><<<1, 64, 0, stream>>>(ws + OFF_S3, ws + OFF_Q3, ws + OFF_N2, g3, b3, ws + OFF_SC3, ws + OFF_SH3);
    bn_apply<64><<<(int)(NSITE2 * 64 / 256), 256, 0, stream>>>(c3, m1, ws + OFF_SC3, ws + OFF_SH3, NSITE2);

    conv3x3_tile<64, 128, 16><<<(int)(NSITE2 / 16), 256, 0, stream>>>(c3, W4, m1, c4, BB, PH, PW);
    bn_stats<128><<<1280, 256, 0, stream>>>(c4, m1, ws + OFF_S4, ws + OFF_Q4, nullptr, NSITE2);
    bn_param<128><<<1, 128, 0, stream>>>(ws + OFF_S4, ws + OFF_Q4, ws + OFF_N2, g4, b4, ws + OFF_SC4, ws + OFF_SH4);
    bn_apply<128><<<(int)(NSITE2 * 128 / 256), 256, 0, stream>>>(c4, m1, ws + OFF_SC4, ws + OFF_SH4, NSITE2);

    maxpool_k<128><<<(int)(NSITE3 * 128 / 256), 256, 0, stream>>>(c4, m1, p2, m2, BB, PH, PW, QH, QW);

    gates_lstm<<<(int)(NSITE3 / 16), 256, 0, stream>>>(p2, Wl, bl, m2, gout);

    fc1_k<<<256, 256, 0, stream>>>(gout, lw1, lb1, y1);

    fc2_k<<<(int)((BB * 420L + 255) / 256), 256, 0, stream>>>(y1, lw2, lb2, out);
}

// Round 3
// 5673.442 us; speedup vs baseline: 13.4187x; 13.4187x over previous
//
#include <hip/hip_runtime.h>
#include <hip/hip_bf16.h>
#include <math.h>

using bf16 = __hip_bfloat16;

typedef short s8v __attribute__((ext_vector_type(8)));   // 8 bf16 bit-pattern (4 VGPRs)
typedef float f4v __attribute__((ext_vector_type(4)));   // MFMA accumulator

// ---------------- problem dims ----------------
static constexpr int  BB  = 2048;
static constexpr int  IH  = 23, IW = 31;   // stage 1 spatial
static constexpr int  PH  = 11, PW = 15;   // after pool1
static constexpr int  QH  = 5,  QW = 7;    // after pool2
static constexpr long NSITE1 = (long)BB * IH * IW;   // 1,460,224 = 64*22,816
static constexpr long NSITE2 = (long)BB * PH * PW;   //   337,920 = 64*5,280
static constexpr long NSITE3 = (long)BB * QH * QW;   //    71,680 = 32*2,240

// ---------------- workspace layout (same total as round 1: 187,449,344 B) ----------------
static constexpr long OFF_S1 = 0,   OFF_Q1 = 64;
static constexpr long OFF_S2 = 128, OFF_Q2 = 192;
static constexpr long OFF_S3 = 256, OFF_Q3 = 320;
static constexpr long OFF_S4 = 384, OFF_Q4 = 512;
static constexpr long OFF_N1 = 640, OFF_N2 = 641;
static constexpr long OFF_SC1 = 704,  OFF_SH1 = 768;
static constexpr long OFF_SC2 = 832,  OFF_SH2 = 896;
static constexpr long OFF_SC3 = 960,  OFF_SH3 = 1024;
static constexpr long OFF_SC4 = 1088, OFF_SH4 = 1216;
static constexpr long OFF_M0 = 2048;
static constexpr long OFF_M1 = OFF_M0 + NSITE1;
static constexpr long OFF_M2 = OFF_M1 + NSITE2;
static constexpr long OFF_BF = 1871872;             // float offset where bf16 area starts
static constexpr long SZ_A   = 43253760L;           // bf16 elems per region
// bf16 weight stashes carved from dead phases of bufA/bufB (see launch ordering):
static constexpr long WB2_A = 25000000L;   // [9][32][32]  = 9,216   (live: conv2; bufA slack past c1)
static constexpr long WB3_B = 22000000L;   // [9][64][32]  = 18,432  (live: conv3; bufB slack past c3)
static constexpr long WB4_B = 22100000L;   // [9][128][64] = 73,728  (live: conv4; bufB slack past c3)
static constexpr long WBL_A = 20000000L;   // [9][1024][128]=1,179,648 (live: gates; bufA past gout)

__device__ __forceinline__ float sigmoidf_(float x) { return 1.f / (1.f + __expf(-x)); }
__device__ __forceinline__ float b2f(bf16 v) { return __bfloat162float(v); }
__device__ __forceinline__ bf16  f2b(float v) { return __float2bfloat16(v); }

// load 8 consecutive bf16 (16B aligned) -> 8 floats
__device__ __forceinline__ void ld8(const bf16* p, float* f) {
    union { uint4 u; unsigned short s[8]; } cv;
    cv.u = *(const uint4*)p;
#pragma unroll
    for (int i = 0; i < 8; i++) f[i] = __uint_as_float(((unsigned int)cv.s[i]) << 16);
}

// ---------------- weight convert+transpose: W[tap][cin][cout] f32 -> wb[tap][cout][cinp] bf16 ----------------
__global__ void cvt_w_k(const float* __restrict__ W, bf16* __restrict__ wb,
                        int CIN, int CINP, int COUT, int total) {
    int idx = blockIdx.x * 256 + threadIdx.x;
    if (idx >= total) return;
    int ci  = idx % CINP;
    int t2  = idx / CINP;
    int co  = t2 % COUT;
    int tap = t2 / COUT;
    wb[idx] = (ci < CIN) ? f2b(W[((long)(tap * CIN + ci)) * COUT + co]) : f2b(0.f);
}

// ---------------- prep: int mask -> float, xm = bf16(x*m) ----------------
__global__ void prep_k(const float* __restrict__ x, const int* __restrict__ mask,
                       float* __restrict__ m0, bf16* __restrict__ xm) {
    long idx = (long)blockIdx.x * 256 + threadIdx.x;
    if (idx >= NSITE1) return;
    float m = (mask[idx] != 0) ? 1.f : 0.f;
    m0[idx] = m;
    xm[idx * 2 + 0] = f2b(x[idx * 2 + 0] * m);
    xm[idx * 2 + 1] = f2b(x[idx * 2 + 1] * m);
}

// ---------------- conv1: 2->16, naive VALU (tiny: 1.7 GF) ----------------
__global__ void conv1_k(const bf16* __restrict__ xm, const float* __restrict__ Wt,
                        const float* __restrict__ m0, bf16* __restrict__ out) {
    const int CIN = 2, COUT = 16, H = IH, W = IW;
    long idx = (long)blockIdx.x * 256 + threadIdx.x;
    long total = NSITE1 * COUT;
    if (idx >= total) return;
    int co = idx % COUT; long site = idx / COUT;
    if (m0[site] == 0.f) { out[idx] = f2b(0.f); return; }
    int w = (int)(site % W); long t2 = site / W; int h = (int)(t2 % H);
    float acc = 0.f;
    for (int kh = 0; kh < 3; kh++) {
        int hh = h + kh - 1; if (hh < 0 || hh >= H) continue;
        for (int kw = 0; kw < 3; kw++) {
            int ww = w + kw - 1; if (ww < 0 || ww >= W) continue;
            long ns = site + (long)(kh - 1) * W + (kw - 1);
            const bf16* ip = xm + ns * CIN;
            const float* wp = Wt + ((kh * 3 + kw) * CIN) * COUT + co;
            acc += b2f(ip[0]) * wp[0] + b2f(ip[1]) * wp[COUT];
        }
    }
    out[idx] = f2b(acc);
}

// ---------------- MFMA direct conv 3x3 SAME ----------------
// M=64 sites/block (4 m-tiles), 4 waves. Wave (wm,wn) covers MT_W m-tiles x NT_W n-tiles.
// A[m=lane&15][k=quad*8+j] loaded straight from global (bf16 [site][CIN] rows);
// B[k][n=lane&15] from wb[tap][cout][CINP] (k along cinp, contiguous 16B).
// For CIN=16 (conv2) CINP=32: k>=16 rows of B are zero, A reads spill into the next
// site's row (valid memory) and are multiplied by B=0 -> exact.
template<int CIN, int CINP, int COUT, int KK, int MT_W, int NT_W, int H, int W>
__global__ void conv_mfma(const bf16* __restrict__ in, const bf16* __restrict__ wb,
                          const float* __restrict__ mask, bf16* __restrict__ out) {
    constexpr int NT = COUT / 16;
    constexpr int NWN = NT / NT_W;            // waves along N
    const int tid = threadIdx.x;
    const int wv = tid >> 6;
    const int L  = tid & 63;
    const int q  = (L >> 4);                  // quad
    const int lm = L & 15;
    const int wn = wv % NWN;
    const int wm = wv / NWN;
    const int mt0 = wm * MT_W;
    const long base = (long)blockIdx.x * 64;

    // per-lane site geometry for my MT_W m-rows
    int hh[MT_W], ww[MT_W];
    long siteA[MT_W];
#pragma unroll
    for (int i = 0; i < MT_W; i++) {
        long s = base + (mt0 + i) * 16 + lm;
        siteA[i] = s;
        int wq = (int)(s % W); long t2 = s / W;
        hh[i] = (int)(t2 % H); ww[i] = wq;
    }

    f4v acc[MT_W][NT_W];
#pragma unroll
    for (int i = 0; i < MT_W; i++)
#pragma unroll
        for (int j = 0; j < NT_W; j++) acc[i][j] = (f4v){0.f, 0.f, 0.f, 0.f};

    for (int tap = 0; tap < 9; tap++) {
        const int dh = tap / 3 - 1, dw = tap % 3 - 1;
#pragma unroll
        for (int kk = 0; kk < KK; kk++) {
            s8v a[MT_W];
#pragma unroll
            for (int i = 0; i < MT_W; i++) {
                int nh = hh[i] + dh, nw = ww[i] + dw;
                bool ok = (nh >= 0) & (nh < H) & (nw >= 0) & (nw < W);
                a[i] = (s8v){0, 0, 0, 0, 0, 0, 0, 0};
                if (ok) {
                    long ns = siteA[i] + (long)dh * W + dw;
                    a[i] = *(const s8v*)(in + ns * CIN + kk * 32 + q * 8);
                }
            }
#pragma unroll
            for (int j = 0; j < NT_W; j++) {
                int co = (wn * NT_W + j) * 16 + lm;
                s8v b = *(const s8v*)(wb + ((long)(tap * COUT + co)) * CINP + kk * 32 + q * 8);
#pragma unroll
                for (int i = 0; i < MT_W; i++)
                    acc[i][j] = __builtin_amdgcn_mfma_f32_16x16x32_bf16(a[i], b, acc[i][j], 0, 0, 0);
            }
        }
    }
    // epilogue: D[row=q*4+r][col=lane&15], masked write
#pragma unroll
    for (int i = 0; i < MT_W; i++) {
#pragma unroll
        for (int r = 0; r < 4; r++) {
            long so = base + (mt0 + i) * 16 + q * 4 + r;
            float mk = mask[so];
#pragma unroll
            for (int j = 0; j < NT_W; j++) {
                int co = (wn * NT_W + j) * 16 + lm;
                out[so * COUT + co] = f2b(mk > 0.f ? acc[i][j][r] : 0.f);
            }
        }
    }
}

// ---------------- BN stats ----------------
template<int C>
__global__ void bn_stats(const bf16* __restrict__ v, const float* __restrict__ mask,
                         float* __restrict__ sum, float* __restrict__ sumsq,
                         float* __restrict__ count, long nsites) {
    __shared__ float s_sum[C], s_ss[C];
    __shared__ float s_cnt;
    int tid = threadIdx.x;
    if (tid < C) { s_sum[tid] = 0.f; s_ss[tid] = 0.f; }
    if (tid == 0) s_cnt = 0.f;
    __syncthreads();
    const int c = tid % C;
    long total = nsites * C;
    long stride = (long)gridDim.x * blockDim.x;
    float ls = 0.f, lss = 0.f, lc = 0.f;
    for (long e = (long)blockIdx.x * blockDim.x + tid; e < total; e += stride) {
        float x = b2f(v[e]);
        ls += x; lss += x * x;
        if (count != nullptr && c == 0) lc += (mask[e / C] > 0.f) ? 1.f : 0.f;
    }
    atomicAdd(&s_sum[c], ls);
    atomicAdd(&s_ss[c], lss);
    if (count != nullptr && c == 0) atomicAdd(&s_cnt, lc);
    __syncthreads();
    if (tid < C) { atomicAdd(&sum[tid], s_sum[tid]); atomicAdd(&sumsq[tid], s_ss[tid]); }
    if (count != nullptr && tid == 0) atomicAdd(count, s_cnt);
}

template<int C>
__global__ void bn_param(const float* __restrict__ sum, const float* __restrict__ ss,
                         const float* __restrict__ count,
                         const float* __restrict__ g, const float* __restrict__ b,
                         float* __restrict__ scale, float* __restrict__ shift) {
    int c = threadIdx.x;
    if (c >= C) return;
    float n = fmaxf(count[0], 1.f);
    float mean = sum[c] / n;
    float var  = ss[c] / n - mean * mean;
    float sc = (1.f / sqrtf(var + 1e-4f)) * g[c];
    scale[c] = sc;
    shift[c] = b[c] - mean * sc;
}

template<int C>
__global__ void bn_apply(bf16* __restrict__ v, const float* __restrict__ mask,
                         const float* __restrict__ scale, const float* __restrict__ shift,
                         long nsites) {
    long idx = (long)blockIdx.x * 256 + threadIdx.x;
    if (idx >= nsites * C) return;
    int c = idx % C; long site = idx / C;
    float val = 0.f;
    if (mask[site] > 0.f) val = fmaxf(b2f(v[idx]) * scale[c] + shift[c], 0.f);
    v[idx] = f2b(val);
}

// ---------------- maxpool 3x3 stride 2 VALID + mask pool ----------------
template<int C>
__global__ void maxpool_k(const bf16* __restrict__ in, const float* __restrict__ min_,
                          bf16* __restrict__ out, float* __restrict__ mout,
                          int B, int H, int W, int OH, int OW) {
    long idx = (long)blockIdx.x * 256 + threadIdx.x;
    long total = (long)B * OH * OW * C;
    if (idx >= total) return;
    int c = idx % C; long osite = idx / C;
    int ow = (int)(osite % OW); long t2 = osite / OW; int oh = (int)(t2 % OH); long b = t2 / OH;
    float mm = 0.f, p = -1e30f;
    for (int kh = 0; kh < 3; kh++)
    for (int kw = 0; kw < 3; kw++) {
        int h = oh * 2 + kh, w = ow * 2 + kw;
        long is = ((long)b * H + h) * W + w;
        float mv = min_[is];
        if (mv > 0.f) { mm = 1.f; p = fmaxf(p, b2f(in[is * C + c])); }
    }
    out[idx] = f2b((mm > 0.f) ? p : 0.f);
    if (c == 0) mout[osite] = mm;
}

// ---------------- ConvLSTM gates via MFMA + in-register LSTM epilogue ----------------
// M=32 sites/block (2 m-tiles), 4 waves; wave wv owns channels c in [wv*64,(wv+1)*64)
// = 4 n-tiles, each with gates i (n=c), o (n=512+c), g (n=768+c): all three land in the
// SAME lane and reg because 512,768 are multiples of 16. f-gate skipped (c0=0).
__global__ void gates_mfma(const bf16* __restrict__ p2, const bf16* __restrict__ wbl,
                           const float* __restrict__ bl, const float* __restrict__ m2,
                           bf16* __restrict__ gout) {
    const int tid = threadIdx.x;
    const int wv = tid >> 6;
    const int L  = tid & 63;
    const int q  = L >> 4;
    const int lm = L & 15;
    const long base = (long)blockIdx.x * 32;

    int hh[2], ww[2];
    long siteA[2];
#pragma unroll
    for (int i = 0; i < 2; i++) {
        long s = base + i * 16 + lm;
        siteA[i] = s;
        ww[i] = (int)(s % QW); hh[i] = (int)((s / QW) % QH);
    }

    f4v acc[2][4][3];   // [mtile][ntile][gate i/o/g]
#pragma unroll
    for (int i = 0; i < 2; i++)
#pragma unroll
        for (int j = 0; j < 4; j++)
#pragma unroll
            for (int g = 0; g < 3; g++) acc[i][j][g] = (f4v){0.f, 0.f, 0.f, 0.f};

    for (int tap = 0; tap < 9; tap++) {
        const int dh = tap / 3 - 1, dw = tap % 3 - 1;
#pragma unroll
        for (int kk = 0; kk < 4; kk++) {
            s8v a[2];
#pragma unroll
            for (int i = 0; i < 2; i++) {
                int nh = hh[i] + dh, nw = ww[i] + dw;
                bool ok = (nh >= 0) & (nh < QH) & (nw >= 0) & (nw < QW);
                a[i] = (s8v){0, 0, 0, 0, 0, 0, 0, 0};
                if (ok) {
                    long ns = siteA[i] + (long)dh * QW + dw;
                    a[i] = *(const s8v*)(p2 + ns * 128 + kk * 32 + q * 8);
                }
            }
#pragma unroll
            for (int j = 0; j < 4; j++) {
                int c = wv * 64 + j * 16 + lm;
                const bf16* wrow = wbl + (long)tap * 1024 * 128 + kk * 32 + q * 8;
                s8v bi = *(const s8v*)(wrow + (long)c * 128);
                s8v bo = *(const s8v*)(wrow + (long)(512 + c) * 128);
                s8v bg = *(const s8v*)(wrow + (long)(768 + c) * 128);
#pragma unroll
                for (int i = 0; i < 2; i++) {
                    acc[i][j][0] = __builtin_amdgcn_mfma_f32_16x16x32_bf16(a[i], bi, acc[i][j][0], 0, 0, 0);
                    acc[i][j][1] = __builtin_amdgcn_mfma_f32_16x16x32_bf16(a[i], bo, acc[i][j][1], 0, 0, 0);
                    acc[i][j][2] = __builtin_amdgcn_mfma_f32_16x16x32_bf16(a[i], bg, acc[i][j][2], 0, 0, 0);
                }
            }
        }
    }
    // epilogue: all in registers; D[row=q*4+r][col=lm]
#pragma unroll
    for (int j = 0; j < 4; j++) {
        int c = wv * 64 + j * 16 + lm;
        float bi = bl[c], bo = bl[512 + c], bg = bl[768 + c];
#pragma unroll
        for (int i = 0; i < 2; i++) {
#pragma unroll
            for (int r = 0; r < 4; r++) {
                long so = base + i * 16 + q * 4 + r;
                float m = m2[so];
                float val = 0.f;
                if (m > 0.f) {
                    float iv = acc[i][j][0][r] + bi;
                    float ov = acc[i][j][1][r] + bo;
                    float gv = acc[i][j][2][r] + bg;
                    float ct = sigmoidf_(iv) * tanhf(gv);
                    val = sigmoidf_(ov) * tanhf(ct);
                }
                gout[so * 256 + c] = f2b(val);
            }
        }
    }
}

// ---------------- FC1: y1[b,j] = relu(sum_k flat[b,k]*lw1[k,j]+lb1[j]) ----------------
// flat[b, k=c*35+hw] lives at gout[(b*35+hw)*256 + c]
__global__ void fc1_k(const bf16* __restrict__ gout, const float* __restrict__ lw1,
                      const float* __restrict__ lb1, bf16* __restrict__ y1) {
    int j  = (blockIdx.x % 4) * 256 + threadIdx.x;
    int b0 = (blockIdx.x / 4) * 32;
    float acc[32];
#pragma unroll
    for (int t = 0; t < 32; t++) acc[t] = 0.f;
    for (int hw = 0; hw < 35; hw++) {
        for (int c8 = 0; c8 < 256; c8 += 8) {
            float w[8];
#pragma unroll
            for (int i = 0; i < 8; i++)
                w[i] = lw1[(long)((c8 + i) * 35 + hw) * 1024 + j];
#pragma unroll
            for (int t = 0; t < 32; t++) {
                float f[8];
                ld8(&gout[((long)(b0 + t) * 35 + hw) * 256 + c8], f);
#pragma unroll
                for (int i = 0; i < 8; i++) acc[t] += f[i] * w[i];
            }
        }
    }
    float bias = lb1[j];
#pragma unroll
    for (int t = 0; t < 32; t++)
        y1[(long)(b0 + t) * 1024 + j] = f2b(fmaxf(acc[t] + bias, 0.f));
}

// ---------------- FC2 ----------------
__global__ void fc2_k(const bf16* __restrict__ y1, const float* __restrict__ lw2,
                      const float* __restrict__ lb2, float* __restrict__ out) {
    long idx = (long)blockIdx.x * 256 + threadIdx.x;
    long total = (long)BB * 420;
    if (idx >= total) return;
    int j = (int)(idx % 420); long b = idx / 420;
    float acc = lb2[j];
    const bf16* yr = y1 + b * 1024;
    for (int k8 = 0; k8 < 1024; k8 += 8) {
        float f[8];
        ld8(yr + k8, f);
#pragma unroll
        for (int i = 0; i < 8; i++) acc += f[i] * lw2[(long)(k8 + i) * 420 + j];
    }
    out[idx] = acc;
}

// ---------------- launch ----------------
extern "C" void kernel_launch(void* const* d_in, const int* in_sizes, int n_in,
                              void* d_out, int out_size, void* d_ws, size_t ws_size,
                              hipStream_t stream) {
    const float* x    = (const float*)d_in[0];
    const int*   mask = (const int*)d_in[1];
    const float* W1 = (const float*)d_in[2];
    const float* g1 = (const float*)d_in[3];
    const float* b1 = (const float*)d_in[4];
    const float* W2 = (const float*)d_in[5];
    const float* g2 = (const float*)d_in[6];
    const float* b2 = (const float*)d_in[7];
    const float* W3 = (const float*)d_in[8];
    const float* g3 = (const float*)d_in[9];
    const float* b3 = (const float*)d_in[10];
    const float* W4 = (const float*)d_in[11];
    const float* g4 = (const float*)d_in[12];
    const float* b4 = (const float*)d_in[13];
    const float* Wl = (const float*)d_in[14];
    const float* bl = (const float*)d_in[15];
    const float* lw1 = (const float*)d_in[16];
    const float* lb1 = (const float*)d_in[17];
    const float* lw2 = (const float*)d_in[18];
    const float* lb2 = (const float*)d_in[19];
    float* out = (float*)d_out;

    float* ws = (float*)d_ws;
    float* m0 = ws + OFF_M0;
    float* m1 = ws + OFF_M1;
    float* m2 = ws + OFF_M2;
    bf16* bufA = (bf16*)(ws + OFF_BF);
    bf16* bufB = bufA + SZ_A;

    bf16* c1   = bufA;            // [NSITE1,16]
    bf16* xm   = bufB;            // [NSITE1,2]  (dead after conv1)
    bf16* c2   = bufB;            // [NSITE1,32]
    bf16* p1   = bufA;            // [NSITE2,32]
    bf16* c3   = bufB;            // [NSITE2,64]
    bf16* c4   = bufA;            // [NSITE2,128]
    bf16* p2   = bufB;            // [NSITE3,128]
    bf16* gout = bufA;            // [NSITE3,256]
    bf16* y1   = bufB;            // [2048,1024]
    bf16* wb2  = bufA + WB2_A;
    bf16* wb3  = bufB + WB3_B;
    bf16* wb4  = bufB + WB4_B;
    bf16* wbl  = bufA + WBL_A;

    hipMemsetAsync(ws, 0, 4096, stream);   // BN stat accumulators

    prep_k<<<(int)((NSITE1 + 255) / 256), 256, 0, stream>>>(x, mask, m0, xm);
    // wb2 lives in bufA past c1's end: safe to convert immediately
    cvt_w_k<<<(9216 + 255) / 256, 256, 0, stream>>>(W2, wb2, 16, 32, 32, 9216);

    conv1_k<<<(int)(NSITE1 * 16 / 256), 256, 0, stream>>>(xm, W1, m0, c1);
    bn_stats<16><<<1280, 256, 0, stream>>>(c1, m0, ws + OFF_S1, ws + OFF_Q1, ws + OFF_N1, NSITE1);
    bn_param<16><<<1, 16, 0, stream>>>(ws + OFF_S1, ws + OFF_Q1, ws + OFF_N1, g1, b1, ws + OFF_SC1, ws + OFF_SH1);
    bn_apply<16><<<(int)(NSITE1 * 16 / 256), 256, 0, stream>>>(c1, m0, ws + OFF_SC1, ws + OFF_SH1, NSITE1);

    // conv2: 16->32  (CIN 16, CINP 32, KK=1, wave = 2mt x 1nt)
    conv_mfma<16, 32, 32, 1, 2, 1, IH, IW><<<(int)(NSITE1 / 64), 256, 0, stream>>>(c1, wb2, m0, c2);
    bn_stats<32><<<1280, 256, 0, stream>>>(c2, m0, ws + OFF_S2, ws + OFF_Q2, nullptr, NSITE1);
    bn_param<32><<<1, 32, 0, stream>>>(ws + OFF_S2, ws + OFF_Q2, ws + OFF_N1, g2, b2, ws + OFF_SC2, ws + OFF_SH2);
    bn_apply<32><<<(int)(NSITE1 * 32 / 256), 256, 0, stream>>>(c2, m0, ws + OFF_SC2, ws + OFF_SH2, NSITE1);

    maxpool_k<32><<<(int)(NSITE2 * 32 / 256), 256, 0, stream>>>(c2, m0, p1, m1, BB, IH, IW, PH, PW);

    // c2 (all of bufB) dead now: convert wb3, wb4 into bufB slack past c3's end
    cvt_w_k<<<(18432 + 255) / 256, 256, 0, stream>>>(W3, wb3, 32, 32, 64, 18432);
    cvt_w_k<<<(73728 + 255) / 256, 256, 0, stream>>>(W4, wb4, 64, 64, 128, 73728);

    // conv3: 32->64 (KK=1, wave = 4mt x 1nt)
    conv_mfma<32, 32, 64, 1, 4, 1, PH, PW><<<(int)(NSITE2 / 64), 256, 0, stream>>>(p1, wb3, m1, c3);
    bn_stats<64><<<1280, 256, 0, stream>>>(c3, m1, ws + OFF_S3, ws + OFF_Q3, ws + OFF_N2, NSITE2);
    bn_param<64><<<1, 64, 0, stream>>>(ws + OFF_S3, ws + OFF_Q3, ws + OFF_N2, g3, b3, ws + OFF_SC3, ws + OFF_SH3);
    bn_apply<64><<<(int)(NSITE2 * 64 / 256), 256, 0, stream>>>(c3, m1, ws + OFF_SC3, ws + OFF_SH3, NSITE2);

    // conv4: 64->128 (KK=2, wave = 4mt x 2nt)
    conv_mfma<64, 64, 128, 2, 4, 2, PH, PW><<<(int)(NSITE2 / 64), 256, 0, stream>>>(c3, wb4, m1, c4);
    bn_stats<128><<<1280, 256, 0, stream>>>(c4, m1, ws + OFF_S4, ws + OFF_Q4, nullptr, NSITE2);
    bn_param<128><<<1, 128, 0, stream>>>(ws + OFF_S4, ws + OFF_Q4, ws + OFF_N2, g4, b4, ws + OFF_SC4, ws + OFF_SH4);
    bn_apply<128><<<(int)(NSITE2 * 128 / 256), 256, 0, stream>>>(c4, m1, ws + OFF_SC4, ws + OFF_SH4, NSITE2);

    maxpool_k<128><<<(int)(NSITE3 * 128 / 256), 256, 0, stream>>>(c4, m1, p2, m2, BB, PH, PW, QH, QW);

    // c4 (bufA) dead now: convert wbl into bufA past gout's end
    cvt_w_k<<<(1179648 + 255) / 256, 256, 0, stream>>>(Wl, wbl, 128, 128, 1024, 1179648);

    gates_mfma<<<(int)(NSITE3 / 32), 256, 0, stream>>>(p2, wbl, bl, m2, gout);

    fc1_k<<<256, 256, 0, stream>>>(gout, lw1, lb1, y1);

    fc2_k<<<(int)((BB * 420L + 255) / 256), 256, 0, stream>>>(y1, lw2, lb2, out);
}

// Round 4
// 2417.853 us; speedup vs baseline: 31.4868x; 2.3465x over previous
//
#include <hip/hip_runtime.h>
#include <hip/hip_bf16.h>
#include <math.h>

using bf16 = __hip_bfloat16;

typedef short s8v __attribute__((ext_vector_type(8)));   // 8 bf16 bit-pattern (4 VGPRs)
typedef float f4v __attribute__((ext_vector_type(4)));   // MFMA accumulator

// ---------------- problem dims ----------------
static constexpr int  BB  = 2048;
static constexpr int  IH  = 23, IW = 31;   // stage 1 spatial
static constexpr int  PH  = 11, PW = 15;   // after pool1
static constexpr int  QH  = 5,  QW = 7;    // after pool2
static constexpr long NSITE1 = (long)BB * IH * IW;   // 1,460,224 = 64*22,816
static constexpr long NSITE2 = (long)BB * PH * PW;   //   337,920 = 64*5,280
static constexpr long NSITE3 = (long)BB * QH * QW;   //    71,680 = 32*2,240

// ---------------- workspace layout (same total as round 1: 187,449,344 B) ----------------
static constexpr long OFF_S1 = 0,   OFF_Q1 = 64;
static constexpr long OFF_S2 = 128, OFF_Q2 = 192;
static constexpr long OFF_S3 = 256, OFF_Q3 = 320;
static constexpr long OFF_S4 = 384, OFF_Q4 = 512;
static constexpr long OFF_N1 = 640, OFF_N2 = 641;
static constexpr long OFF_SC1 = 704,  OFF_SH1 = 768;
static constexpr long OFF_SC2 = 832,  OFF_SH2 = 896;
static constexpr long OFF_SC3 = 960,  OFF_SH3 = 1024;
static constexpr long OFF_SC4 = 1088, OFF_SH4 = 1216;
static constexpr long OFF_M0 = 2048;
static constexpr long OFF_M1 = OFF_M0 + NSITE1;
static constexpr long OFF_M2 = OFF_M1 + NSITE2;
static constexpr long OFF_BF = 1871872;             // float offset where bf16 area starts
static constexpr long SZ_A   = 43253760L;           // bf16 elems per region
// bf16 weight stashes carved from dead phases of bufA/bufB (see launch ordering):
static constexpr long WB2_A  = 25000000L;  // [9][32][32]  = 9,216   (bufA past c1)
static constexpr long WB3_B  = 22000000L;  // [9][64][32]  = 18,432  (bufB past c3)
static constexpr long WB4_B  = 22100000L;  // [9][128][64] = 73,728  (bufB past c3)
static constexpr long WBL_A  = 20000000L;  // [9][1024][128]=1,179,648 (bufA past gout)
static constexpr long WFC1_B = 23000000L;  // [1024][8960] = 9,175,040 (bufB, live pool1->fc1)

__device__ __forceinline__ float sigmoidf_(float x) { return 1.f / (1.f + __expf(-x)); }
__device__ __forceinline__ float b2f(bf16 v) { return __bfloat162float(v); }
__device__ __forceinline__ bf16  f2b(float v) { return __float2bfloat16(v); }

// load 8 consecutive bf16 (16B aligned) -> 8 floats
__device__ __forceinline__ void ld8(const bf16* p, float* f) {
    union { uint4 u; unsigned short s[8]; } cv;
    cv.u = *(const uint4*)p;
#pragma unroll
    for (int i = 0; i < 8; i++) f[i] = __uint_as_float(((unsigned int)cv.s[i]) << 16);
}
// store 8 floats -> 8 consecutive bf16 (16B aligned)
__device__ __forceinline__ void st8(bf16* p, const float* f) {
    union { uint4 u; bf16 h[8]; } cv;
#pragma unroll
    for (int i = 0; i < 8; i++) cv.h[i] = f2b(f[i]);
    *(uint4*)p = cv.u;
}

// ---------------- weight convert+transpose: W[tap][cin][cout] f32 -> wb[tap][cout][cinp] bf16 ----------------
__global__ void cvt_w_k(const float* __restrict__ W, bf16* __restrict__ wb,
                        int CIN, int CINP, int COUT, int total) {
    int idx = blockIdx.x * 256 + threadIdx.x;
    if (idx >= total) return;
    int ci  = idx % CINP;
    int t2  = idx / CINP;
    int co  = t2 % COUT;
    int tap = t2 / COUT;
    wb[idx] = (ci < CIN) ? f2b(W[((long)(tap * CIN + ci)) * COUT + co]) : f2b(0.f);
}

// ---------------- FC1 weight: lw1[k=c*35+hw][j] f32 -> wfc1[j][k'=hw*256+c] bf16 ----------------
__global__ void cvt_fc1_k(const float* __restrict__ lw1, bf16* __restrict__ wfc1) {
    long idx = (long)blockIdx.x * 256 + threadIdx.x;
    if (idx >= 9175040L) return;
    int c  = (int)(idx & 255);
    int hw = (int)((idx >> 8) % 35);
    int j  = (int)(idx / 8960);
    wfc1[idx] = f2b(lw1[(long)(c * 35 + hw) * 1024 + j]);
}

// ---------------- prep: int mask -> float, xm = bf16(x*m) ----------------
__global__ void prep_k(const float* __restrict__ x, const int* __restrict__ mask,
                       float* __restrict__ m0, bf16* __restrict__ xm) {
    long idx = (long)blockIdx.x * 256 + threadIdx.x;
    if (idx >= NSITE1) return;
    float m = (mask[idx] != 0) ? 1.f : 0.f;
    m0[idx] = m;
    xm[idx * 2 + 0] = f2b(x[idx * 2 + 0] * m);
    xm[idx * 2 + 1] = f2b(x[idx * 2 + 1] * m);
}

// ---------------- conv1: 2->16, one site per thread (uniform weight loads) ----------------
__global__ void conv1_k(const bf16* __restrict__ xm, const float* __restrict__ Wt,
                        const float* __restrict__ m0, bf16* __restrict__ out) {
    const int H = IH, W = IW;
    long site = (long)blockIdx.x * 256 + threadIdx.x;
    if (site >= NSITE1) return;
    float acc[16];
#pragma unroll
    for (int i = 0; i < 16; i++) acc[i] = 0.f;
    float mk = m0[site];
    if (mk > 0.f) {
        int w = (int)(site % W); int h = (int)((site / W) % H);
        for (int tap = 0; tap < 9; tap++) {
            int dh = tap / 3 - 1, dw = tap % 3 - 1;
            int nh = h + dh, nw = w + dw;
            if (nh < 0 || nh >= H || nw < 0 || nw >= W) continue;
            long ns = site + (long)dh * W + dw;
            float i0 = b2f(xm[ns * 2 + 0]), i1 = b2f(xm[ns * 2 + 1]);
            const float* wp = Wt + tap * 32;   // [2][16]
#pragma unroll
            for (int co = 0; co < 16; co++) acc[co] += i0 * wp[co] + i1 * wp[16 + co];
        }
    }
    st8(out + site * 16, acc);
    st8(out + site * 16 + 8, acc + 8);
}

// ---------------- MFMA direct conv 3x3 SAME ----------------
template<int CIN, int CINP, int COUT, int KK, int MT_W, int NT_W, int H, int W>
__global__ void conv_mfma(const bf16* __restrict__ in, const bf16* __restrict__ wb,
                          const float* __restrict__ mask, bf16* __restrict__ out) {
    constexpr int NT = COUT / 16;
    constexpr int NWN = NT / NT_W;            // waves along N
    const int tid = threadIdx.x;
    const int wv = tid >> 6;
    const int L  = tid & 63;
    const int q  = (L >> 4);                  // quad
    const int lm = L & 15;
    const int wn = wv % NWN;
    const int wm = wv / NWN;
    const int mt0 = wm * MT_W;
    const long base = (long)blockIdx.x * 64;

    int hh[MT_W], ww[MT_W];
    long siteA[MT_W];
#pragma unroll
    for (int i = 0; i < MT_W; i++) {
        long s = base + (mt0 + i) * 16 + lm;
        siteA[i] = s;
        int wq = (int)(s % W); long t2 = s / W;
        hh[i] = (int)(t2 % H); ww[i] = wq;
    }

    f4v acc[MT_W][NT_W];
#pragma unroll
    for (int i = 0; i < MT_W; i++)
#pragma unroll
        for (int j = 0; j < NT_W; j++) acc[i][j] = (f4v){0.f, 0.f, 0.f, 0.f};

    for (int tap = 0; tap < 9; tap++) {
        const int dh = tap / 3 - 1, dw = tap % 3 - 1;
#pragma unroll
        for (int kk = 0; kk < KK; kk++) {
            s8v a[MT_W];
#pragma unroll
            for (int i = 0; i < MT_W; i++) {
                int nh = hh[i] + dh, nw = ww[i] + dw;
                bool ok = (nh >= 0) & (nh < H) & (nw >= 0) & (nw < W);
                a[i] = (s8v){0, 0, 0, 0, 0, 0, 0, 0};
                if (ok) {
                    long ns = siteA[i] + (long)dh * W + dw;
                    a[i] = *(const s8v*)(in + ns * CIN + kk * 32 + q * 8);
                }
            }
#pragma unroll
            for (int j = 0; j < NT_W; j++) {
                int co = (wn * NT_W + j) * 16 + lm;
                s8v b = *(const s8v*)(wb + ((long)(tap * COUT + co)) * CINP + kk * 32 + q * 8);
#pragma unroll
                for (int i = 0; i < MT_W; i++)
                    acc[i][j] = __builtin_amdgcn_mfma_f32_16x16x32_bf16(a[i], b, acc[i][j], 0, 0, 0);
            }
        }
    }
#pragma unroll
    for (int i = 0; i < MT_W; i++) {
#pragma unroll
        for (int r = 0; r < 4; r++) {
            long so = base + (mt0 + i) * 16 + q * 4 + r;
            float mk = mask[so];
#pragma unroll
            for (int j = 0; j < NT_W; j++) {
                int co = (wn * NT_W + j) * 16 + lm;
                out[so * COUT + co] = f2b(mk > 0.f ? acc[i][j][r] : 0.f);
            }
        }
    }
}

// ---------------- BN stats (bf16x8 vector loads) ----------------
template<int C>
__global__ void bn_stats(const bf16* __restrict__ v, const float* __restrict__ mask,
                         float* __restrict__ sum, float* __restrict__ sumsq,
                         float* __restrict__ count, long nsites) {
    __shared__ float s_sum[C], s_ss[C];
    __shared__ float s_cnt;
    int tid = threadIdx.x;
    if (tid < C) { s_sum[tid] = 0.f; s_ss[tid] = 0.f; }
    if (tid == 0) s_cnt = 0.f;
    __syncthreads();
    const long total8 = nsites * C / 8;
    const long stride = (long)gridDim.x * 256;
    const int c0 = (int)((((long)blockIdx.x * 256 + tid) * 8) % C);  // fixed per thread
    float ls[8], lss[8];
#pragma unroll
    for (int i = 0; i < 8; i++) { ls[i] = 0.f; lss[i] = 0.f; }
    float lc = 0.f;
    for (long e8 = (long)blockIdx.x * 256 + tid; e8 < total8; e8 += stride) {
        long e0 = e8 * 8;
        float f[8];
        ld8(v + e0, f);
#pragma unroll
        for (int i = 0; i < 8; i++) { ls[i] += f[i]; lss[i] += f[i] * f[i]; }
        if (count != nullptr && c0 == 0) lc += (mask[e0 / C] > 0.f) ? 1.f : 0.f;
    }
#pragma unroll
    for (int i = 0; i < 8; i++) {
        atomicAdd(&s_sum[c0 + i], ls[i]);
        atomicAdd(&s_ss[c0 + i], lss[i]);
    }
    if (count != nullptr && c0 == 0) atomicAdd(&s_cnt, lc);
    __syncthreads();
    if (tid < C) { atomicAdd(&sum[tid], s_sum[tid]); atomicAdd(&sumsq[tid], s_ss[tid]); }
    if (count != nullptr && tid == 0) atomicAdd(count, s_cnt);
}

template<int C>
__global__ void bn_param(const float* __restrict__ sum, const float* __restrict__ ss,
                         const float* __restrict__ count,
                         const float* __restrict__ g, const float* __restrict__ b,
                         float* __restrict__ scale, float* __restrict__ shift) {
    int c = threadIdx.x;
    if (c >= C) return;
    float n = fmaxf(count[0], 1.f);
    float mean = sum[c] / n;
    float var  = ss[c] / n - mean * mean;
    float sc = (1.f / sqrtf(var + 1e-4f)) * g[c];
    scale[c] = sc;
    shift[c] = b[c] - mean * sc;
}

// ---------------- BN apply (+ReLU, masked), in-place, bf16x8 ----------------
template<int C>
__global__ void bn_apply(bf16* __restrict__ v, const float* __restrict__ mask,
                         const float* __restrict__ scale, const float* __restrict__ shift,
                         long nsites) {
    long i8 = (long)blockIdx.x * 256 + threadIdx.x;
    if (i8 >= nsites * C / 8) return;
    long e0 = i8 * 8;
    int c0 = (int)(e0 % C);
    long site = e0 / C;
    float mk = mask[site];
    float f[8], o[8];
    ld8(v + e0, f);
#pragma unroll
    for (int i = 0; i < 8; i++)
        o[i] = (mk > 0.f) ? fmaxf(f[i] * scale[c0 + i] + shift[c0 + i], 0.f) : 0.f;
    st8(v + e0, o);
}

// ---------------- maxpool 3x3 stride 2 VALID + mask pool, bf16x8 ----------------
template<int C>
__global__ void maxpool_k(const bf16* __restrict__ in, const float* __restrict__ min_,
                          bf16* __restrict__ out, float* __restrict__ mout,
                          int B, int H, int W, int OH, int OW) {
    long i8 = (long)blockIdx.x * 256 + threadIdx.x;
    long total8 = (long)B * OH * OW * C / 8;
    if (i8 >= total8) return;
    long e0 = i8 * 8;
    int c0 = (int)(e0 % C);
    long osite = e0 / C;
    int ow = (int)(osite % OW); long t2 = osite / OW; int oh = (int)(t2 % OH); long b = t2 / OH;
    float mm = 0.f, p[8];
#pragma unroll
    for (int i = 0; i < 8; i++) p[i] = -1e30f;
    for (int kh = 0; kh < 3; kh++)
    for (int kw = 0; kw < 3; kw++) {
        int h = oh * 2 + kh, w = ow * 2 + kw;
        long is = ((long)b * H + h) * W + w;
        float mv = min_[is];
        if (mv > 0.f) {
            mm = 1.f;
            float f[8];
            ld8(in + is * C + c0, f);
#pragma unroll
            for (int i = 0; i < 8; i++) p[i] = fmaxf(p[i], f[i]);
        }
    }
    float o[8];
#pragma unroll
    for (int i = 0; i < 8; i++) o[i] = (mm > 0.f) ? p[i] : 0.f;
    st8(out + e0, o);
    if (c0 == 0) mout[osite] = mm;
}

// ---------------- ConvLSTM gates via MFMA + in-register LSTM epilogue ----------------
__global__ void gates_mfma(const bf16* __restrict__ p2, const bf16* __restrict__ wbl,
                           const float* __restrict__ bl, const float* __restrict__ m2,
                           bf16* __restrict__ gout) {
    const int tid = threadIdx.x;
    const int wv = tid >> 6;
    const int L  = tid & 63;
    const int q  = L >> 4;
    const int lm = L & 15;
    const long base = (long)blockIdx.x * 32;

    int hh[2], ww[2];
    long siteA[2];
#pragma unroll
    for (int i = 0; i < 2; i++) {
        long s = base + i * 16 + lm;
        siteA[i] = s;
        ww[i] = (int)(s % QW); hh[i] = (int)((s / QW) % QH);
    }

    f4v acc[2][4][3];   // [mtile][ntile][gate i/o/g]
#pragma unroll
    for (int i = 0; i < 2; i++)
#pragma unroll
        for (int j = 0; j < 4; j++)
#pragma unroll
            for (int g = 0; g < 3; g++) acc[i][j][g] = (f4v){0.f, 0.f, 0.f, 0.f};

    for (int tap = 0; tap < 9; tap++) {
        const int dh = tap / 3 - 1, dw = tap % 3 - 1;
#pragma unroll
        for (int kk = 0; kk < 4; kk++) {
            s8v a[2];
#pragma unroll
            for (int i = 0; i < 2; i++) {
                int nh = hh[i] + dh, nw = ww[i] + dw;
                bool ok = (nh >= 0) & (nh < QH) & (nw >= 0) & (nw < QW);
                a[i] = (s8v){0, 0, 0, 0, 0, 0, 0, 0};
                if (ok) {
                    long ns = siteA[i] + (long)dh * QW + dw;
                    a[i] = *(const s8v*)(p2 + ns * 128 + kk * 32 + q * 8);
                }
            }
#pragma unroll
            for (int j = 0; j < 4; j++) {
                int c = wv * 64 + j * 16 + lm;
                const bf16* wrow = wbl + (long)tap * 1024 * 128 + kk * 32 + q * 8;
                s8v bi = *(const s8v*)(wrow + (long)c * 128);
                s8v bo = *(const s8v*)(wrow + (long)(512 + c) * 128);
                s8v bg = *(const s8v*)(wrow + (long)(768 + c) * 128);
#pragma unroll
                for (int i = 0; i < 2; i++) {
                    acc[i][j][0] = __builtin_amdgcn_mfma_f32_16x16x32_bf16(a[i], bi, acc[i][j][0], 0, 0, 0);
                    acc[i][j][1] = __builtin_amdgcn_mfma_f32_16x16x32_bf16(a[i], bo, acc[i][j][1], 0, 0, 0);
                    acc[i][j][2] = __builtin_amdgcn_mfma_f32_16x16x32_bf16(a[i], bg, acc[i][j][2], 0, 0, 0);
                }
            }
        }
    }
#pragma unroll
    for (int j = 0; j < 4; j++) {
        int c = wv * 64 + j * 16 + lm;
        float bi = bl[c], bo = bl[512 + c], bg = bl[768 + c];
#pragma unroll
        for (int i = 0; i < 2; i++) {
#pragma unroll
            for (int r = 0; r < 4; r++) {
                long so = base + i * 16 + q * 4 + r;
                float m = m2[so];
                float val = 0.f;
                if (m > 0.f) {
                    float iv = acc[i][j][0][r] + bi;
                    float ov = acc[i][j][1][r] + bo;
                    float gv = acc[i][j][2][r] + bg;
                    float ct = sigmoidf_(iv) * tanhf(gv);
                    val = sigmoidf_(ov) * tanhf(ct);
                }
                gout[so * 256 + c] = f2b(val);
            }
        }
    }
}

// ---------------- FC1 via MFMA ----------------
// A = gout viewed as [2048][8960] (k' = hw*256+c), Wt = wfc1 [1024][8960] same k-order.
// Block 256 thr = 4 waves (2x2); block tile 64M x 64N; wave tile 32x32.
// Grid = 32 m-blocks x 16 n-blocks = 512.
__global__ void fc1_mfma(const bf16* __restrict__ A, const bf16* __restrict__ Wt,
                         const float* __restrict__ lb1, bf16* __restrict__ y1) {
    const int tid = threadIdx.x;
    const int wv = tid >> 6;
    const int L  = tid & 63;
    const int q  = L >> 4, lm = L & 15;
    const int wm = wv >> 1, wn = wv & 1;
    const int bm = blockIdx.x & 31;
    const int bn = blockIdx.x >> 5;
    const int m0 = bm * 64 + wm * 32;
    const int n0 = bn * 64 + wn * 32;

    f4v acc[2][2];
#pragma unroll
    for (int i = 0; i < 2; i++)
#pragma unroll
        for (int j = 0; j < 2; j++) acc[i][j] = (f4v){0.f, 0.f, 0.f, 0.f};

    const bf16* a0p = A  + (long)(m0 + lm) * 8960 + q * 8;
    const bf16* a1p = a0p + (long)16 * 8960;
    const bf16* b0p = Wt + (long)(n0 + lm) * 8960 + q * 8;
    const bf16* b1p = b0p + (long)16 * 8960;

#pragma unroll 2
    for (int k0 = 0; k0 < 8960; k0 += 32) {
        s8v a0 = *(const s8v*)(a0p + k0);
        s8v a1 = *(const s8v*)(a1p + k0);
        s8v b0 = *(const s8v*)(b0p + k0);
        s8v b1 = *(const s8v*)(b1p + k0);
        acc[0][0] = __builtin_amdgcn_mfma_f32_16x16x32_bf16(a0, b0, acc[0][0], 0, 0, 0);
        acc[0][1] = __builtin_amdgcn_mfma_f32_16x16x32_bf16(a0, b1, acc[0][1], 0, 0, 0);
        acc[1][0] = __builtin_amdgcn_mfma_f32_16x16x32_bf16(a1, b0, acc[1][0], 0, 0, 0);
        acc[1][1] = __builtin_amdgcn_mfma_f32_16x16x32_bf16(a1, b1, acc[1][1], 0, 0, 0);
    }
#pragma unroll
    for (int i = 0; i < 2; i++) {
#pragma unroll
        for (int j = 0; j < 2; j++) {
            int nn = n0 + j * 16 + lm;
            float bias = lb1[nn];
#pragma unroll
            for (int r = 0; r < 4; r++) {
                int mm = m0 + i * 16 + q * 4 + r;
                y1[(long)mm * 1024 + nn] = f2b(fmaxf(acc[i][j][r] + bias, 0.f));
            }
        }
    }
}

// ---------------- FC2 ----------------
__global__ void fc2_k(const bf16* __restrict__ y1, const float* __restrict__ lw2,
                      const float* __restrict__ lb2, float* __restrict__ out) {
    long idx = (long)blockIdx.x * 256 + threadIdx.x;
    long total = (long)BB * 420;
    if (idx >= total) return;
    int j = (int)(idx % 420); long b = idx / 420;
    float acc = lb2[j];
    const bf16* yr = y1 + b * 1024;
    for (int k8 = 0; k8 < 1024; k8 += 8) {
        float f[8];
        ld8(yr + k8, f);
#pragma unroll
        for (int i = 0; i < 8; i++) acc += f[i] * lw2[(long)(k8 + i) * 420 + j];
    }
    out[idx] = acc;
}

// ---------------- launch ----------------
extern "C" void kernel_launch(void* const* d_in, const int* in_sizes, int n_in,
                              void* d_out, int out_size, void* d_ws, size_t ws_size,
                              hipStream_t stream) {
    const float* x    = (const float*)d_in[0];
    const int*   mask = (const int*)d_in[1];
    const float* W1 = (const float*)d_in[2];
    const float* g1 = (const float*)d_in[3];
    const float* b1 = (const float*)d_in[4];
    const float* W2 = (const float*)d_in[5];
    const float* g2 = (const float*)d_in[6];
    const float* b2 = (const float*)d_in[7];
    const float* W3 = (const float*)d_in[8];
    const float* g3 = (const float*)d_in[9];
    const float* b3 = (const float*)d_in[10];
    const float* W4 = (const float*)d_in[11];
    const float* g4 = (const float*)d_in[12];
    const float* b4 = (const float*)d_in[13];
    const float* Wl = (const float*)d_in[14];
    const float* bl = (const float*)d_in[15];
    const float* lw1 = (const float*)d_in[16];
    const float* lb1 = (const float*)d_in[17];
    const float* lw2 = (const float*)d_in[18];
    const float* lb2 = (const float*)d_in[19];
    float* out = (float*)d_out;

    float* ws = (float*)d_ws;
    float* m0 = ws + OFF_M0;
    float* m1 = ws + OFF_M1;
    float* m2 = ws + OFF_M2;
    bf16* bufA = (bf16*)(ws + OFF_BF);
    bf16* bufB = bufA + SZ_A;

    bf16* c1   = bufA;            // [NSITE1,16]
    bf16* xm   = bufB;            // [NSITE1,2]  (dead after conv1)
    bf16* c2   = bufB;            // [NSITE1,32]
    bf16* p1   = bufA;            // [NSITE2,32]
    bf16* c3   = bufB;            // [NSITE2,64]
    bf16* c4   = bufA;            // [NSITE2,128]
    bf16* p2   = bufB;            // [NSITE3,128]
    bf16* gout = bufA;            // [NSITE3,256] == A[2048][8960]
    bf16* y1   = bufB;            // [2048,1024]
    bf16* wb2  = bufA + WB2_A;
    bf16* wb3  = bufB + WB3_B;
    bf16* wb4  = bufB + WB4_B;
    bf16* wbl  = bufA + WBL_A;
    bf16* wfc1 = bufB + WFC1_B;

    hipMemsetAsync(ws, 0, 4096, stream);   // BN stat accumulators

    prep_k<<<(int)((NSITE1 + 255) / 256), 256, 0, stream>>>(x, mask, m0, xm);
    cvt_w_k<<<(9216 + 255) / 256, 256, 0, stream>>>(W2, wb2, 16, 32, 32, 9216);

    conv1_k<<<(int)((NSITE1 + 255) / 256), 256, 0, stream>>>(xm, W1, m0, c1);
    bn_stats<16><<<1280, 256, 0, stream>>>(c1, m0, ws + OFF_S1, ws + OFF_Q1, ws + OFF_N1, NSITE1);
    bn_param<16><<<1, 16, 0, stream>>>(ws + OFF_S1, ws + OFF_Q1, ws + OFF_N1, g1, b1, ws + OFF_SC1, ws + OFF_SH1);
    bn_apply<16><<<(int)(NSITE1 * 16 / 8 / 256), 256, 0, stream>>>(c1, m0, ws + OFF_SC1, ws + OFF_SH1, NSITE1);

    conv_mfma<16, 32, 32, 1, 2, 1, IH, IW><<<(int)(NSITE1 / 64), 256, 0, stream>>>(c1, wb2, m0, c2);
    bn_stats<32><<<1280, 256, 0, stream>>>(c2, m0, ws + OFF_S2, ws + OFF_Q2, nullptr, NSITE1);
    bn_param<32><<<1, 32, 0, stream>>>(ws + OFF_S2, ws + OFF_Q2, ws + OFF_N1, g2, b2, ws + OFF_SC2, ws + OFF_SH2);
    bn_apply<32><<<(int)(NSITE1 * 32 / 8 / 256), 256, 0, stream>>>(c2, m0, ws + OFF_SC2, ws + OFF_SH2, NSITE1);

    maxpool_k<32><<<(int)(NSITE2 * 32 / 8 / 256), 256, 0, stream>>>(c2, m0, p1, m1, BB, IH, IW, PH, PW);

    // c2 (bufB) dead: convert wb3, wb4, wfc1 into bufB slack
    cvt_w_k<<<(18432 + 255) / 256, 256, 0, stream>>>(W3, wb3, 32, 32, 64, 18432);
    cvt_w_k<<<(73728 + 255) / 256, 256, 0, stream>>>(W4, wb4, 64, 64, 128, 73728);
    cvt_fc1_k<<<(int)((9175040L + 255) / 256), 256, 0, stream>>>(lw1, wfc1);

    conv_mfma<32, 32, 64, 1, 4, 1, PH, PW><<<(int)(NSITE2 / 64), 256, 0, stream>>>(p1, wb3, m1, c3);
    bn_stats<64><<<1280, 256, 0, stream>>>(c3, m1, ws + OFF_S3, ws + OFF_Q3, ws + OFF_N2, NSITE2);
    bn_param<64><<<1, 64, 0, stream>>>(ws + OFF_S3, ws + OFF_Q3, ws + OFF_N2, g3, b3, ws + OFF_SC3, ws + OFF_SH3);
    bn_apply<64><<<(int)(NSITE2 * 64 / 8 / 256), 256, 0, stream>>>(c3, m1, ws + OFF_SC3, ws + OFF_SH3, NSITE2);

    conv_mfma<64, 64, 128, 2, 4, 2, PH, PW><<<(int)(NSITE2 / 64), 256, 0, stream>>>(c3, wb4, m1, c4);
    bn_stats<128><<<1280, 256, 0, stream>>>(c4, m1, ws + OFF_S4, ws + OFF_Q4, nullptr, NSITE2);
    bn_param<128><<<1, 128, 0, stream>>>(ws + OFF_S4, ws + OFF_Q4, ws + OFF_N2, g4, b4, ws + OFF_SC4, ws + OFF_SH4);
    bn_apply<128><<<(int)(NSITE2 * 128 / 8 / 256), 256, 0, stream>>>(c4, m1, ws + OFF_SC4, ws + OFF_SH4, NSITE2);

    maxpool_k<128><<<(int)(NSITE3 * 128 / 8 / 256), 256, 0, stream>>>(c4, m1, p2, m2, BB, PH, PW, QH, QW);

    // c4 (bufA) dead: convert wbl into bufA past gout's end
    cvt_w_k<<<(1179648 + 255) / 256, 256, 0, stream>>>(Wl, wbl, 128, 128, 1024, 1179648);

    gates_mfma<<<(int)(NSITE3 / 32), 256, 0, stream>>>(p2, wbl, bl, m2, gout);

    fc1_mfma<<<512, 256, 0, stream>>>(gout, wfc1, lb1, y1);

    fc2_k<<<(int)((BB * 420L + 255) / 256), 256, 0, stream>>>(y1, lw2, lb2, out);
}